// Round 1
// baseline (340.980 us; speedup 1.0000x reference)
//
#include <hip/hip_runtime.h>
#include <cstdint>
#include <cstddef>

#define NB    32          // batches
#define SEQ   1024        // sequence length
#define DIN   256
#define HID   512
#define MTOT  32768       // NB*SEQ

typedef _Float16 half_t;
typedef _Float16 half8  __attribute__((ext_vector_type(8)));
typedef _Float16 half4v __attribute__((ext_vector_type(4)));
typedef float    f32x4  __attribute__((ext_vector_type(4)));

typedef __attribute__((address_space(1))) const void* gas_ptr;
typedef __attribute__((address_space(3))) void*       las_ptr;

// ---------------- f32 -> f16 convert ----------------
__global__ void cvt_kernel(const float* __restrict__ src, half_t* __restrict__ dst, int n4) {
    int i = blockIdx.x * blockDim.x + threadIdx.x;
    if (i < n4) {
        f32x4 v = ((const f32x4*)src)[i];
        half4v h;
        h[0] = (half_t)v[0]; h[1] = (half_t)v[1]; h[2] = (half_t)v[2]; h[3] = (half_t)v[3];
        ((half4v*)dst)[i] = h;
    }
}

__global__ void pack_bias(const float* __restrict__ bv, const float* __restrict__ bk,
                          const float* __restrict__ bq, float* __restrict__ dst) {
    int t = threadIdx.x;
    if (t < HID) {
        dst[t]         = bv[t];
        dst[HID + t]   = bk[t];
        dst[2*HID + t] = bq[t];
    }
}

// ---------------- GEMM template ----------------
// C[m][n] = sum_k A[m][k] * B[n][k]   (both operands k-contiguous, "B^T" layout)
// MODE 0: QKV proj. bias+relu, f16 out. z=0 -> transposed into out2 (vT[b][h][m]); z=1,2 -> row-major k16/q16.
// MODE 1: S gemm. f32 out, no bias.
// MODE 2: PV gemm. f16 out row-major, no bias.
// MODE 3: out proj. f32 out, bias+relu.
template<int MODE>
__global__ __launch_bounds__(256, 2) void gemm_k(
    const half_t* __restrict__ A, long lda, long a_bs,
    const half_t* __restrict__ Bw, long ldb, long b_bs,
    void* __restrict__ Out, long ldo, long o_bs,
    const float* __restrict__ bias,
    int Kdim, half_t* __restrict__ out2)
{
    __shared__ alignas(16) half_t As[128 * 32];
    __shared__ alignas(16) half_t Bs[128 * 32];

    const int t    = threadIdx.x;
    const int lane = t & 63;
    const int wave = t >> 6;
    const int wm   = wave >> 1;       // 0..1
    const int wn   = wave & 1;        // 0..1
    const int lanen = lane & 15;
    const int quad  = lane >> 4;      // 0..3
    const int z     = blockIdx.z;
    const long m0 = (long)blockIdx.x * 128;
    const long n0 = (long)blockIdx.y * 128;

    const half_t* Ab = A  + (long)z * a_bs;
    const half_t* Bb = Bw + (long)z * b_bs;

    f32x4 acc[4][4];
#pragma unroll
    for (int i = 0; i < 4; i++)
#pragma unroll
        for (int j = 0; j < 4; j++)
            acc[i][j] = f32x4{0.f, 0.f, 0.f, 0.f};

    // staging: 512 chunks of 16B per tile, 2 per thread. chunk c -> row c>>2, kchunk c&3.
    // wave-contiguous lds placement: chunk c lands at lds byte c*16.
    const int c0 = t, c1 = t + 256;
    const int r0 = c0 >> 2, kc0 = c0 & 3;
    const int r1 = c1 >> 2, kc1 = c1 & 3;

    const half_t* gA0 = Ab + (m0 + r0) * lda + kc0 * 8;
    const half_t* gA1 = Ab + (m0 + r1) * lda + kc1 * 8;
    const half_t* gB0 = Bb + (n0 + r0) * ldb + kc0 * 8;
    const half_t* gB1 = Bb + (n0 + r1) * ldb + kc1 * 8;
    half_t* lA0 = &As[c0 * 8];
    half_t* lA1 = &As[c1 * 8];
    half_t* lB0 = &Bs[c0 * 8];
    half_t* lB1 = &Bs[c1 * 8];

    int aoff[4], boff[4];
#pragma unroll
    for (int i = 0; i < 4; i++) aoff[i] = (wm * 64 + i * 16 + lanen) * 32 + quad * 8;
#pragma unroll
    for (int j = 0; j < 4; j++) boff[j] = (wn * 64 + j * 16 + lanen) * 32 + quad * 8;

    for (int k0 = 0; k0 < Kdim; k0 += 32) {
        __builtin_amdgcn_global_load_lds((gas_ptr)(gA0 + k0), (las_ptr)lA0, 16, 0, 0);
        __builtin_amdgcn_global_load_lds((gas_ptr)(gA1 + k0), (las_ptr)lA1, 16, 0, 0);
        __builtin_amdgcn_global_load_lds((gas_ptr)(gB0 + k0), (las_ptr)lB0, 16, 0, 0);
        __builtin_amdgcn_global_load_lds((gas_ptr)(gB1 + k0), (las_ptr)lB1, 16, 0, 0);
        __syncthreads();

        half8 af[4], bf[4];
#pragma unroll
        for (int i = 0; i < 4; i++) af[i] = *(const half8*)&As[aoff[i]];
#pragma unroll
        for (int j = 0; j < 4; j++) bf[j] = *(const half8*)&Bs[boff[j]];
#pragma unroll
        for (int i = 0; i < 4; i++)
#pragma unroll
            for (int j = 0; j < 4; j++)
                acc[i][j] = __builtin_amdgcn_mfma_f32_16x16x32_f16(af[i], bf[j], acc[i][j], 0, 0, 0);
        __syncthreads();
    }

    // ---------- epilogue ----------
    // C/D layout: col = lane&15, row = quad*4 + reg  (regs are 4 consecutive rows)
#pragma unroll
    for (int i = 0; i < 4; i++) {
        long mrow = m0 + wm * 64 + i * 16 + quad * 4;
#pragma unroll
        for (int j = 0; j < 4; j++) {
            long gn = n0 + wn * 64 + j * 16 + lanen;
            f32x4 v = acc[i][j];
            if (MODE == 0) {
                float bb = bias[z * HID + gn];
                half_t h0 = (half_t)fmaxf(v[0] + bb, 0.f);
                half_t h1 = (half_t)fmaxf(v[1] + bb, 0.f);
                half_t h2 = (half_t)fmaxf(v[2] + bb, 0.f);
                half_t h3 = (half_t)fmaxf(v[3] + bb, 0.f);
                if (z == 0) {
                    // V -> transposed vT[b][h][m]; 4 regs = consecutive m -> one 8B store
                    long bidx = mrow >> 10;
                    long pos  = mrow & 1023;
                    half4v pk; pk[0] = h0; pk[1] = h1; pk[2] = h2; pk[3] = h3;
                    *(half4v*)(out2 + ((bidx * HID + gn) << 10) + pos) = pk;
                } else {
                    half_t* o = (half_t*)Out + (long)(z - 1) * o_bs;
                    o[(mrow + 0) * ldo + gn] = h0;
                    o[(mrow + 1) * ldo + gn] = h1;
                    o[(mrow + 2) * ldo + gn] = h2;
                    o[(mrow + 3) * ldo + gn] = h3;
                }
            } else if (MODE == 1) {
                float* o = (float*)Out + (long)z * o_bs;
#pragma unroll
                for (int r = 0; r < 4; r++) o[(mrow + r) * ldo + gn] = v[r];
            } else if (MODE == 2) {
                half_t* o = (half_t*)Out + (long)z * o_bs;
#pragma unroll
                for (int r = 0; r < 4; r++) o[(mrow + r) * ldo + gn] = (half_t)v[r];
            } else {
                float* o = (float*)Out;
                float bb = bias[gn];
#pragma unroll
                for (int r = 0; r < 4; r++) o[(mrow + r) * ldo + gn] = fmaxf(v[r] + bb, 0.f);
            }
        }
    }
}

// ---------------- softmax: one block per row; P (normalized) f16 written in place ----------------
__global__ __launch_bounds__(256) void softmax_k(float* __restrict__ Sg) {
    long row = blockIdx.x;
    float* rp = Sg + (row << 10);
    int t = threadIdx.x;
    int lane = t & 63, wave = t >> 6;

    f32x4 x = ((const f32x4*)rp)[t];
    float mx = fmaxf(fmaxf(x[0], x[1]), fmaxf(x[2], x[3]));
#pragma unroll
    for (int o = 32; o > 0; o >>= 1) mx = fmaxf(mx, __shfl_xor(mx, o, 64));
    __shared__ float red[8];
    if (lane == 0) red[wave] = mx;
    __syncthreads();
    mx = fmaxf(fmaxf(red[0], red[1]), fmaxf(red[2], red[3]));

    float e0 = __expf(x[0] - mx), e1 = __expf(x[1] - mx);
    float e2 = __expf(x[2] - mx), e3 = __expf(x[3] - mx);
    float s = e0 + e1 + e2 + e3;
#pragma unroll
    for (int o = 32; o > 0; o >>= 1) s += __shfl_xor(s, o, 64);
    if (lane == 0) red[4 + wave] = s;
    __syncthreads();
    s = red[4] + red[5] + red[6] + red[7];
    float inv = 1.f / s;

    half4v p;
    p[0] = (half_t)(e0 * inv); p[1] = (half_t)(e1 * inv);
    p[2] = (half_t)(e2 * inv); p[3] = (half_t)(e3 * inv);
    ((half4v*)rp)[t] = p;   // all reads of this row completed before the barriers above
}

// ---------------- host ----------------
extern "C" void kernel_launch(void* const* d_in, const int* in_sizes, int n_in,
                              void* d_out, int out_size, void* d_ws, size_t ws_size,
                              hipStream_t stream) {
    const float* h  = (const float*)d_in[0];
    const float* Wv = (const float*)d_in[1];
    const float* bv = (const float*)d_in[2];
    const float* Wk = (const float*)d_in[3];
    const float* bk = (const float*)d_in[4];
    const float* Wq = (const float*)d_in[5];
    const float* bq = (const float*)d_in[6];
    const float* Wo = (const float*)d_in[7];
    const float* bo = (const float*)d_in[8];

    uint8_t* ws = (uint8_t*)d_ws;
    size_t off = 0;
    auto alloc = [&](size_t bytes) { size_t o = off; off += (bytes + 255) & ~(size_t)255; return o; };

    half_t* W16   = (half_t*)(ws + alloc((size_t)3 * HID * DIN * 2)); // [Wv][Wk][Wq]
    half_t* Wo16  = (half_t*)(ws + alloc((size_t)DIN * HID * 2));
    float*  biasq = (float*)(ws + alloc((size_t)3 * HID * 4));        // [bv][bk][bq]
    half_t* k16   = (half_t*)(ws + alloc((size_t)MTOT * HID * 2));
    half_t* q16   = (half_t*)(ws + alloc((size_t)MTOT * HID * 2));    // later reused as O16 (per-group, stream-ordered)
    half_t* vT    = (half_t*)(ws + alloc((size_t)MTOT * HID * 2));    // [b][h][m]
    size_t h16_off = alloc((size_t)MTOT * DIN * 2);
    half_t* h16   = (half_t*)(ws + h16_off);
    // S buffer overlaps h16 region onward (h16 dead after K1)
    float* Sbuf = (float*)(ws + h16_off);
    half_t* O16 = q16;  // q dead after its group's S gemm; O written strictly after

    size_t s_per_batch = (size_t)SEQ * SEQ * 4;
    size_t s_avail = ws_size > h16_off ? ws_size - h16_off : 0;
    int GB = (int)(s_avail / s_per_batch);
    if (GB < 1)  GB = 1;
    if (GB > NB) GB = NB;

    // K0: conversions
    cvt_kernel<<<dim3((MTOT * DIN / 4 + 255) / 256), 256, 0, stream>>>(h, h16, MTOT * DIN / 4);
    cvt_kernel<<<dim3((HID * DIN / 4 + 255) / 256), 256, 0, stream>>>(Wv, W16, HID * DIN / 4);
    cvt_kernel<<<dim3((HID * DIN / 4 + 255) / 256), 256, 0, stream>>>(Wk, W16 + HID * DIN, HID * DIN / 4);
    cvt_kernel<<<dim3((HID * DIN / 4 + 255) / 256), 256, 0, stream>>>(Wq, W16 + 2 * HID * DIN, HID * DIN / 4);
    cvt_kernel<<<dim3((DIN * HID / 4 + 255) / 256), 256, 0, stream>>>(Wo, Wo16, DIN * HID / 4);
    pack_bias<<<dim3(1), 512, 0, stream>>>(bv, bk, bq, biasq);

    // K1: QKV projections (z: 0=V->vT, 1=K, 2=Q)
    gemm_k<0><<<dim3(MTOT / 128, HID / 128, 3), 256, 0, stream>>>(
        h16, DIN, 0,
        W16, DIN, (long)HID * DIN,
        (void*)k16, HID, (long)MTOT * HID,
        biasq, DIN, vT);

    for (int g0 = 0; g0 < NB; g0 += GB) {
        int gb = NB - g0 < GB ? NB - g0 : GB;
        // K2: S = q k^T  (f32)
        gemm_k<1><<<dim3(SEQ / 128, SEQ / 128, gb), 256, 0, stream>>>(
            q16 + (size_t)g0 * SEQ * HID, HID, (long)SEQ * HID,
            k16 + (size_t)g0 * SEQ * HID, HID, (long)SEQ * HID,
            (void*)Sbuf, SEQ, (long)SEQ * SEQ,
            nullptr, HID, nullptr);
        // K3: softmax rows -> P f16 in place
        softmax_k<<<dim3(gb * SEQ), 256, 0, stream>>>(Sbuf);
        // K4: O = P vT
        gemm_k<2><<<dim3(SEQ / 128, HID / 128, gb), 256, 0, stream>>>(
            (const half_t*)Sbuf, 2 * SEQ, (long)2 * SEQ * SEQ,
            vT + (size_t)g0 * HID * SEQ, SEQ, (long)HID * SEQ,
            (void*)(O16 + (size_t)g0 * SEQ * HID), HID, (long)SEQ * HID,
            nullptr, SEQ, nullptr);
    }

    // K5: out = relu(O Wo^T + bo)  (f32 out)
    gemm_k<3><<<dim3(MTOT / 128, DIN / 128, 1), 256, 0, stream>>>(
        O16, HID, 0,
        Wo16, HID, 0,
        d_out, DIN, 0,
        bo, HID, nullptr);

    (void)in_sizes; (void)n_in; (void)out_size;
}

// Round 2
// 301.963 us; speedup vs baseline: 1.1292x; 1.1292x over previous
//
#include <hip/hip_runtime.h>
#include <cstdint>
#include <cstddef>

#define NB    32          // batches
#define SEQ   1024        // sequence length
#define DIN   256
#define HID   512
#define MTOT  32768       // NB*SEQ

typedef _Float16 half_t;
typedef _Float16 half8  __attribute__((ext_vector_type(8)));
typedef _Float16 half4v __attribute__((ext_vector_type(4)));
typedef float    f32x4  __attribute__((ext_vector_type(4)));

typedef __attribute__((address_space(1))) const void* gas_ptr;
typedef __attribute__((address_space(3))) void*       las_ptr;

// ---------------- f32 -> f16 convert ----------------
__global__ void cvt_kernel(const float* __restrict__ src, half_t* __restrict__ dst, int n4) {
    int i = blockIdx.x * blockDim.x + threadIdx.x;
    if (i < n4) {
        f32x4 v = ((const f32x4*)src)[i];
        half4v h;
        h[0] = (half_t)v[0]; h[1] = (half_t)v[1]; h[2] = (half_t)v[2]; h[3] = (half_t)v[3];
        ((half4v*)dst)[i] = h;
    }
}

__global__ void pack_bias(const float* __restrict__ bv, const float* __restrict__ bk,
                          const float* __restrict__ bq, float* __restrict__ dst) {
    int t = threadIdx.x;
    if (t < HID) {
        dst[t]         = bv[t];
        dst[HID + t]   = bk[t];
        dst[2*HID + t] = bq[t];
    }
}

// ---------------- generic GEMM (projections) ----------------
// C[m][n] = sum_k A[m][k] * B[n][k]
// MODE 0: QKV proj. bias+relu, f16 out. z=0 -> transposed into out2 (vT[b][h][m]); z=1,2 -> row-major k16/q16.
// MODE 3: out proj. f32 out, bias+relu.
template<int MODE>
__global__ __launch_bounds__(256, 2) void gemm_k(
    const half_t* __restrict__ A, long lda, long a_bs,
    const half_t* __restrict__ Bw, long ldb, long b_bs,
    void* __restrict__ Out, long ldo, long o_bs,
    const float* __restrict__ bias,
    int Kdim, half_t* __restrict__ out2)
{
    __shared__ alignas(16) half_t As[128 * 32];
    __shared__ alignas(16) half_t Bs[128 * 32];

    const int t    = threadIdx.x;
    const int lane = t & 63;
    const int wave = t >> 6;
    const int wm   = wave >> 1;
    const int wn   = wave & 1;
    const int lanen = lane & 15;
    const int quad  = lane >> 4;
    const int z     = blockIdx.z;
    const long m0 = (long)blockIdx.x * 128;
    const long n0 = (long)blockIdx.y * 128;

    const half_t* Ab = A  + (long)z * a_bs;
    const half_t* Bb = Bw + (long)z * b_bs;

    f32x4 acc[4][4];
#pragma unroll
    for (int i = 0; i < 4; i++)
#pragma unroll
        for (int j = 0; j < 4; j++)
            acc[i][j] = f32x4{0.f, 0.f, 0.f, 0.f};

    const int c0 = t, c1 = t + 256;
    const int r0 = c0 >> 2, kc0 = c0 & 3;
    const int r1 = c1 >> 2, kc1 = c1 & 3;

    const half_t* gA0 = Ab + (m0 + r0) * lda + kc0 * 8;
    const half_t* gA1 = Ab + (m0 + r1) * lda + kc1 * 8;
    const half_t* gB0 = Bb + (n0 + r0) * ldb + kc0 * 8;
    const half_t* gB1 = Bb + (n0 + r1) * ldb + kc1 * 8;
    half_t* lA0 = &As[c0 * 8];
    half_t* lA1 = &As[c1 * 8];
    half_t* lB0 = &Bs[c0 * 8];
    half_t* lB1 = &Bs[c1 * 8];

    int aoff[4], boff[4];
#pragma unroll
    for (int i = 0; i < 4; i++) aoff[i] = (wm * 64 + i * 16 + lanen) * 32 + quad * 8;
#pragma unroll
    for (int j = 0; j < 4; j++) boff[j] = (wn * 64 + j * 16 + lanen) * 32 + quad * 8;

    for (int k0 = 0; k0 < Kdim; k0 += 32) {
        __builtin_amdgcn_global_load_lds((gas_ptr)(gA0 + k0), (las_ptr)lA0, 16, 0, 0);
        __builtin_amdgcn_global_load_lds((gas_ptr)(gA1 + k0), (las_ptr)lA1, 16, 0, 0);
        __builtin_amdgcn_global_load_lds((gas_ptr)(gB0 + k0), (las_ptr)lB0, 16, 0, 0);
        __builtin_amdgcn_global_load_lds((gas_ptr)(gB1 + k0), (las_ptr)lB1, 16, 0, 0);
        __syncthreads();

        half8 af[4], bf[4];
#pragma unroll
        for (int i = 0; i < 4; i++) af[i] = *(const half8*)&As[aoff[i]];
#pragma unroll
        for (int j = 0; j < 4; j++) bf[j] = *(const half8*)&Bs[boff[j]];
#pragma unroll
        for (int i = 0; i < 4; i++)
#pragma unroll
            for (int j = 0; j < 4; j++)
                acc[i][j] = __builtin_amdgcn_mfma_f32_16x16x32_f16(af[i], bf[j], acc[i][j], 0, 0, 0);
        __syncthreads();
    }

    // C/D layout: col = lane&15, row = quad*4 + reg
#pragma unroll
    for (int i = 0; i < 4; i++) {
        long mrow = m0 + wm * 64 + i * 16 + quad * 4;
#pragma unroll
        for (int j = 0; j < 4; j++) {
            long gn = n0 + wn * 64 + j * 16 + lanen;
            f32x4 v = acc[i][j];
            if (MODE == 0) {
                float bb = bias[z * HID + gn];
                half_t h0 = (half_t)fmaxf(v[0] + bb, 0.f);
                half_t h1 = (half_t)fmaxf(v[1] + bb, 0.f);
                half_t h2 = (half_t)fmaxf(v[2] + bb, 0.f);
                half_t h3 = (half_t)fmaxf(v[3] + bb, 0.f);
                if (z == 0) {
                    long bidx = mrow >> 10;
                    long pos  = mrow & 1023;
                    half4v pk; pk[0] = h0; pk[1] = h1; pk[2] = h2; pk[3] = h3;
                    *(half4v*)(out2 + ((bidx * HID + gn) << 10) + pos) = pk;
                } else {
                    half_t* o = (half_t*)Out + (long)(z - 1) * o_bs;
                    o[(mrow + 0) * ldo + gn] = h0;
                    o[(mrow + 1) * ldo + gn] = h1;
                    o[(mrow + 2) * ldo + gn] = h2;
                    o[(mrow + 3) * ldo + gn] = h3;
                }
            } else {
                float* o = (float*)Out;
                float bb = bias[gn];
#pragma unroll
                for (int r = 0; r < 4; r++) o[(mrow + r) * ldo + gn] = fmaxf(v[r] + bb, 0.f);
            }
        }
    }
}

// ---------------- S = q k^T, fused exp epilogue ----------------
// Writes E = exp(s - m_loc) f16 (tile-local row max over this 128-col block),
// plus per-(row, col-block) stats m_loc (Mstat) and l_loc = sum exp (Lstat).
__global__ __launch_bounds__(256, 2) void se_k(
    const half_t* __restrict__ Q, const half_t* __restrict__ K,
    half_t* __restrict__ E, float* __restrict__ Mstat, float* __restrict__ Lstat)
{
    __shared__ alignas(16) half_t As[128 * 32];
    __shared__ alignas(16) half_t Bs[128 * 32];
    __shared__ float redM[2][128];
    __shared__ float redL[2][128];

    const int t    = threadIdx.x;
    const int lane = t & 63;
    const int wave = t >> 6;
    const int wm   = wave >> 1;
    const int wn   = wave & 1;
    const int lanen = lane & 15;
    const int quad  = lane >> 4;
    const int z     = blockIdx.z;
    const int kb    = blockIdx.y;           // col-block
    const long m0 = (long)blockIdx.x * 128;
    const long n0 = (long)kb * 128;

    const half_t* Ab = Q + (long)z * SEQ * HID;
    const half_t* Bb = K + (long)z * SEQ * HID;

    f32x4 acc[4][4];
#pragma unroll
    for (int i = 0; i < 4; i++)
#pragma unroll
        for (int j = 0; j < 4; j++)
            acc[i][j] = f32x4{0.f, 0.f, 0.f, 0.f};

    const int c0 = t, c1 = t + 256;
    const int r0 = c0 >> 2, kc0 = c0 & 3;
    const int r1 = c1 >> 2, kc1 = c1 & 3;

    const half_t* gA0 = Ab + (m0 + r0) * HID + kc0 * 8;
    const half_t* gA1 = Ab + (m0 + r1) * HID + kc1 * 8;
    const half_t* gB0 = Bb + (n0 + r0) * HID + kc0 * 8;
    const half_t* gB1 = Bb + (n0 + r1) * HID + kc1 * 8;
    half_t* lA0 = &As[c0 * 8];
    half_t* lA1 = &As[c1 * 8];
    half_t* lB0 = &Bs[c0 * 8];
    half_t* lB1 = &Bs[c1 * 8];

    int aoff[4], boff[4];
#pragma unroll
    for (int i = 0; i < 4; i++) aoff[i] = (wm * 64 + i * 16 + lanen) * 32 + quad * 8;
#pragma unroll
    for (int j = 0; j < 4; j++) boff[j] = (wn * 64 + j * 16 + lanen) * 32 + quad * 8;

    for (int k0 = 0; k0 < HID; k0 += 32) {
        __builtin_amdgcn_global_load_lds((gas_ptr)(gA0 + k0), (las_ptr)lA0, 16, 0, 0);
        __builtin_amdgcn_global_load_lds((gas_ptr)(gA1 + k0), (las_ptr)lA1, 16, 0, 0);
        __builtin_amdgcn_global_load_lds((gas_ptr)(gB0 + k0), (las_ptr)lB0, 16, 0, 0);
        __builtin_amdgcn_global_load_lds((gas_ptr)(gB1 + k0), (las_ptr)lB1, 16, 0, 0);
        __syncthreads();

        half8 af[4], bf[4];
#pragma unroll
        for (int i = 0; i < 4; i++) af[i] = *(const half8*)&As[aoff[i]];
#pragma unroll
        for (int j = 0; j < 4; j++) bf[j] = *(const half8*)&Bs[boff[j]];
#pragma unroll
        for (int i = 0; i < 4; i++)
#pragma unroll
            for (int j = 0; j < 4; j++)
                acc[i][j] = __builtin_amdgcn_mfma_f32_16x16x32_f16(af[i], bf[j], acc[i][j], 0, 0, 0);
        __syncthreads();
    }

    // ---- epilogue: tile-local row max ----
    float rm[4][4];
#pragma unroll
    for (int i = 0; i < 4; i++)
#pragma unroll
        for (int r = 0; r < 4; r++) {
            float v = fmaxf(fmaxf(acc[i][0][r], acc[i][1][r]), fmaxf(acc[i][2][r], acc[i][3][r]));
#pragma unroll
            for (int off = 8; off > 0; off >>= 1)
                v = fmaxf(v, __shfl_xor(v, off, 64));
            rm[i][r] = v;
        }
    if (lanen == 0) {
#pragma unroll
        for (int i = 0; i < 4; i++)
#pragma unroll
            for (int r = 0; r < 4; r++)
                redM[wn][wm * 64 + i * 16 + quad * 4 + r] = rm[i][r];
    }
    __syncthreads();

    float mf[4][4];
#pragma unroll
    for (int i = 0; i < 4; i++)
#pragma unroll
        for (int r = 0; r < 4; r++) {
            int rl = wm * 64 + i * 16 + quad * 4 + r;
            mf[i][r] = fmaxf(redM[0][rl], redM[1][rl]);
        }

    // ---- exp + row partial sums + E store ----
    half_t* Eb = E + (long)z * SEQ * SEQ;
    float rs[4][4];
#pragma unroll
    for (int i = 0; i < 4; i++)
#pragma unroll
        for (int r = 0; r < 4; r++) rs[i][r] = 0.f;
#pragma unroll
    for (int i = 0; i < 4; i++) {
        long mrow = m0 + wm * 64 + i * 16 + quad * 4;
#pragma unroll
        for (int j = 0; j < 4; j++) {
            long gn = n0 + wn * 64 + j * 16 + lanen;
#pragma unroll
            for (int r = 0; r < 4; r++) {
                float e = __expf(acc[i][j][r] - mf[i][r]);
                rs[i][r] += e;
                Eb[(mrow + r) * SEQ + gn] = (half_t)e;
            }
        }
    }
#pragma unroll
    for (int i = 0; i < 4; i++)
#pragma unroll
        for (int r = 0; r < 4; r++) {
            float v = rs[i][r];
#pragma unroll
            for (int off = 8; off > 0; off >>= 1)
                v += __shfl_xor(v, off, 64);
            rs[i][r] = v;
        }
    if (lanen == 0) {
#pragma unroll
        for (int i = 0; i < 4; i++)
#pragma unroll
            for (int r = 0; r < 4; r++)
                redL[wn][wm * 64 + i * 16 + quad * 4 + r] = rs[i][r];
    }
    __syncthreads();

    if (t < 128) {
        long sidx = ((long)z * 8 + kb) * SEQ + m0 + t;
        Mstat[sidx] = fmaxf(redM[0][t], redM[1][t]);
        Lstat[sidx] = redL[0][t] + redL[1][t];
    }
}

// ---------------- O = P vT with stat-merge rescale + row normalize ----------------
__global__ __launch_bounds__(256, 2) void pv_k(
    const half_t* __restrict__ E, const half_t* __restrict__ vT,
    const float* __restrict__ Mstat, const float* __restrict__ Lstat,
    half_t* __restrict__ O16)
{
    __shared__ alignas(16) half_t As[128 * 32];
    __shared__ alignas(16) half_t Bs[128 * 32];
    __shared__ float scaleS[8][128];
    __shared__ float invS[128];

    const int t    = threadIdx.x;
    const int lane = t & 63;
    const int wave = t >> 6;
    const int wm   = wave >> 1;
    const int wn   = wave & 1;
    const int lanen = lane & 15;
    const int quad  = lane >> 4;
    const int z     = blockIdx.z;
    const long m0 = (long)blockIdx.x * 128;
    const long h0 = (long)blockIdx.y * 128;

    // prologue: merge per-col-block stats for this block's 128 rows
    if (t < 128) {
        float mv[8];
        float M = -1e30f;
#pragma unroll
        for (int kb = 0; kb < 8; kb++) {
            mv[kb] = Mstat[((long)z * 8 + kb) * SEQ + m0 + t];
            M = fmaxf(M, mv[kb]);
        }
        float ls = 0.f;
#pragma unroll
        for (int kb = 0; kb < 8; kb++) {
            float sc = __expf(mv[kb] - M);
            scaleS[kb][t] = sc;
            ls += Lstat[((long)z * 8 + kb) * SEQ + m0 + t] * sc;
        }
        invS[t] = 1.f / ls;
    }
    __syncthreads();

    const half_t* Ab = E  + (long)z * SEQ * SEQ;
    const half_t* Bb = vT + (long)z * HID * SEQ;

    f32x4 acc[4][4];
#pragma unroll
    for (int i = 0; i < 4; i++)
#pragma unroll
        for (int j = 0; j < 4; j++)
            acc[i][j] = f32x4{0.f, 0.f, 0.f, 0.f};

    const int c0 = t, c1 = t + 256;
    const int r0 = c0 >> 2, kc0 = c0 & 3;
    const int r1 = c1 >> 2, kc1 = c1 & 3;

    const half_t* gA0 = Ab + (m0 + r0) * SEQ + kc0 * 8;
    const half_t* gA1 = Ab + (m0 + r1) * SEQ + kc1 * 8;
    const half_t* gB0 = Bb + (h0 + r0) * SEQ + kc0 * 8;
    const half_t* gB1 = Bb + (h0 + r1) * SEQ + kc1 * 8;
    half_t* lA0 = &As[c0 * 8];
    half_t* lA1 = &As[c1 * 8];
    half_t* lB0 = &Bs[c0 * 8];
    half_t* lB1 = &Bs[c1 * 8];

    int aoff[4], boff[4];
#pragma unroll
    for (int i = 0; i < 4; i++) aoff[i] = (wm * 64 + i * 16 + lanen) * 32 + quad * 8;
#pragma unroll
    for (int j = 0; j < 4; j++) boff[j] = (wn * 64 + j * 16 + lanen) * 32 + quad * 8;

    for (int k0 = 0; k0 < SEQ; k0 += 32) {
        __builtin_amdgcn_global_load_lds((gas_ptr)(gA0 + k0), (las_ptr)lA0, 16, 0, 0);
        __builtin_amdgcn_global_load_lds((gas_ptr)(gA1 + k0), (las_ptr)lA1, 16, 0, 0);
        __builtin_amdgcn_global_load_lds((gas_ptr)(gB0 + k0), (las_ptr)lB0, 16, 0, 0);
        __builtin_amdgcn_global_load_lds((gas_ptr)(gB1 + k0), (las_ptr)lB1, 16, 0, 0);
        __syncthreads();

        const int kb = k0 >> 7;
        half8 af[4], bf[4];
#pragma unroll
        for (int i = 0; i < 4; i++) {
            af[i] = *(const half8*)&As[aoff[i]];
            half_t sh = (half_t)scaleS[kb][wm * 64 + i * 16 + lanen];
            af[i] *= sh;   // per-row rescale exp(m_kb - M); A-operand row = lane&15
        }
#pragma unroll
        for (int j = 0; j < 4; j++) bf[j] = *(const half8*)&Bs[boff[j]];
#pragma unroll
        for (int i = 0; i < 4; i++)
#pragma unroll
            for (int j = 0; j < 4; j++)
                acc[i][j] = __builtin_amdgcn_mfma_f32_16x16x32_f16(af[i], bf[j], acc[i][j], 0, 0, 0);
        __syncthreads();
    }

    half_t* o = O16 + (long)z * SEQ * HID;
#pragma unroll
    for (int i = 0; i < 4; i++) {
        long mrow = m0 + wm * 64 + i * 16 + quad * 4;
        int rl = wm * 64 + i * 16 + quad * 4;
#pragma unroll
        for (int j = 0; j < 4; j++) {
            long gn = h0 + wn * 64 + j * 16 + lanen;
#pragma unroll
            for (int r = 0; r < 4; r++)
                o[(mrow + r) * HID + gn] = (half_t)(acc[i][j][r] * invS[rl + r]);
        }
    }
}

// ---------------- host ----------------
extern "C" void kernel_launch(void* const* d_in, const int* in_sizes, int n_in,
                              void* d_out, int out_size, void* d_ws, size_t ws_size,
                              hipStream_t stream) {
    const float* h  = (const float*)d_in[0];
    const float* Wv = (const float*)d_in[1];
    const float* bv = (const float*)d_in[2];
    const float* Wk = (const float*)d_in[3];
    const float* bk = (const float*)d_in[4];
    const float* Wq = (const float*)d_in[5];
    const float* bq = (const float*)d_in[6];
    const float* Wo = (const float*)d_in[7];
    const float* bo = (const float*)d_in[8];

    uint8_t* ws = (uint8_t*)d_ws;
    size_t off = 0;
    auto alloc = [&](size_t bytes) { size_t o = off; off += (bytes + 255) & ~(size_t)255; return o; };

    half_t* W16   = (half_t*)(ws + alloc((size_t)3 * HID * DIN * 2)); // [Wv][Wk][Wq]
    half_t* Wo16  = (half_t*)(ws + alloc((size_t)DIN * HID * 2));
    float*  biasq = (float*)(ws + alloc((size_t)3 * HID * 4));        // [bv][bk][bq]
    half_t* k16   = (half_t*)(ws + alloc((size_t)MTOT * HID * 2));
    half_t* q16   = (half_t*)(ws + alloc((size_t)MTOT * HID * 2));    // reused as O16 per group
    half_t* vT    = (half_t*)(ws + alloc((size_t)MTOT * HID * 2));    // [b][h][m]
    size_t h16_off = alloc((size_t)MTOT * DIN * 2);
    half_t* h16   = (half_t*)(ws + h16_off);
    half_t* O16 = q16;  // q dead after its group's se_k; O written strictly after

    // E + stats overlap the (dead-after-K1) h16 region onward
    size_t s_avail = ws_size > h16_off ? ws_size - h16_off : 0;
    size_t per_batch = (size_t)SEQ * SEQ * 2 + 2 * 8 * SEQ * 4;
    int GB = (int)(s_avail / per_batch);
    if (GB < 1)  GB = 1;
    if (GB > NB) GB = NB;
    half_t* Ebuf  = (half_t*)(ws + h16_off);
    float*  Mstat = (float*)(ws + h16_off + (size_t)GB * SEQ * SEQ * 2);
    float*  Lstat = Mstat + (size_t)GB * 8 * SEQ;

    // K0: conversions
    cvt_kernel<<<dim3((MTOT * DIN / 4 + 255) / 256), 256, 0, stream>>>(h, h16, MTOT * DIN / 4);
    cvt_kernel<<<dim3((HID * DIN / 4 + 255) / 256), 256, 0, stream>>>(Wv, W16, HID * DIN / 4);
    cvt_kernel<<<dim3((HID * DIN / 4 + 255) / 256), 256, 0, stream>>>(Wk, W16 + HID * DIN, HID * DIN / 4);
    cvt_kernel<<<dim3((HID * DIN / 4 + 255) / 256), 256, 0, stream>>>(Wq, W16 + 2 * HID * DIN, HID * DIN / 4);
    cvt_kernel<<<dim3((DIN * HID / 4 + 255) / 256), 256, 0, stream>>>(Wo, Wo16, DIN * HID / 4);
    pack_bias<<<dim3(1), 512, 0, stream>>>(bv, bk, bq, biasq);

    // K1: QKV projections (z: 0=V->vT, 1=K, 2=Q)
    gemm_k<0><<<dim3(MTOT / 128, HID / 128, 3), 256, 0, stream>>>(
        h16, DIN, 0,
        W16, DIN, (long)HID * DIN,
        (void*)k16, HID, (long)MTOT * HID,
        biasq, DIN, vT);

    for (int g0 = 0; g0 < NB; g0 += GB) {
        int gb = NB - g0 < GB ? NB - g0 : GB;
        // K2: E = exp(q k^T - m_loc) + stats
        se_k<<<dim3(SEQ / 128, SEQ / 128, gb), 256, 0, stream>>>(
            q16 + (size_t)g0 * SEQ * HID,
            k16 + (size_t)g0 * SEQ * HID,
            Ebuf, Mstat, Lstat);
        // K4: O = (scaled E) vT / lsum
        pv_k<<<dim3(SEQ / 128, HID / 128, gb), 256, 0, stream>>>(
            Ebuf, vT + (size_t)g0 * HID * SEQ,
            Mstat, Lstat,
            O16 + (size_t)g0 * SEQ * HID);
    }

    // K5: out = relu(O Wo^T + bo)  (f32 out)
    gemm_k<3><<<dim3(MTOT / 128, DIN / 128, 1), 256, 0, stream>>>(
        O16, HID, 0,
        Wo16, HID, 0,
        d_out, DIN, 0,
        bo, HID, nullptr);

    (void)in_sizes; (void)n_in; (void)out_size;
}

// Round 3
// 290.755 us; speedup vs baseline: 1.1727x; 1.0385x over previous
//
#include <hip/hip_runtime.h>
#include <cstdint>
#include <cstddef>

#define NB    32          // batches
#define SEQ   1024        // sequence length
#define DIN   256
#define HID   512
#define MTOT  32768       // NB*SEQ

typedef _Float16 half_t;
typedef _Float16 half8  __attribute__((ext_vector_type(8)));
typedef _Float16 half4v __attribute__((ext_vector_type(4)));
typedef float    f32x4  __attribute__((ext_vector_type(4)));

typedef __attribute__((address_space(1))) const void* gas_ptr;
typedef __attribute__((address_space(3))) void*       las_ptr;

// ---------------- f32 -> f16 convert ----------------
__global__ void cvt_kernel(const float* __restrict__ src, half_t* __restrict__ dst, int n4) {
    int i = blockIdx.x * blockDim.x + threadIdx.x;
    if (i < n4) {
        f32x4 v = ((const f32x4*)src)[i];
        half4v h;
        h[0] = (half_t)v[0]; h[1] = (half_t)v[1]; h[2] = (half_t)v[2]; h[3] = (half_t)v[3];
        ((half4v*)dst)[i] = h;
    }
}

// all 4 weight matrices are HID*DIN == DIN*HID elements; blockIdx.y selects
__global__ void cvt4_kernel(const float* __restrict__ s0, const float* __restrict__ s1,
                            const float* __restrict__ s2, const float* __restrict__ s3,
                            half_t* __restrict__ d0, half_t* __restrict__ d1,
                            half_t* __restrict__ d2, half_t* __restrict__ d3, int n4) {
    int y = blockIdx.y;
    const float* s = y == 0 ? s0 : y == 1 ? s1 : y == 2 ? s2 : s3;
    half_t*      d = y == 0 ? d0 : y == 1 ? d1 : y == 2 ? d2 : d3;
    int i = blockIdx.x * blockDim.x + threadIdx.x;
    if (i < n4) {
        f32x4 v = ((const f32x4*)s)[i];
        half4v h;
        h[0] = (half_t)v[0]; h[1] = (half_t)v[1]; h[2] = (half_t)v[2]; h[3] = (half_t)v[3];
        ((half4v*)d)[i] = h;
    }
}

__global__ void pack_bias(const float* __restrict__ bv, const float* __restrict__ bk,
                          const float* __restrict__ bq, float* __restrict__ dst) {
    int t = threadIdx.x;
    if (t < HID) {
        dst[t]         = bv[t];
        dst[HID + t]   = bk[t];
        dst[2*HID + t] = bq[t];
    }
}

// ---------------- generic GEMM (projections), 128x128 tile ----------------
// C[m][n] = sum_k A[m][k] * B[n][k]
// MODE 0: QKV proj. bias+relu, f16 out. z=0 -> transposed into out2 (vT[b][h][m]); z=1,2 -> row-major.
// MODE 3: out proj. f32 out, bias+relu.
template<int MODE>
__global__ __launch_bounds__(256, 2) void gemm_k(
    const half_t* __restrict__ A, long lda, long a_bs,
    const half_t* __restrict__ Bw, long ldb, long b_bs,
    void* __restrict__ Out, long ldo, long o_bs,
    const float* __restrict__ bias,
    int Kdim, half_t* __restrict__ out2)
{
    __shared__ alignas(16) half_t As[128 * 32];
    __shared__ alignas(16) half_t Bs[128 * 32];

    const int t    = threadIdx.x;
    const int lane = t & 63;
    const int wave = t >> 6;
    const int wm   = wave >> 1;
    const int wn   = wave & 1;
    const int lanen = lane & 15;
    const int quad  = lane >> 4;
    const int z     = blockIdx.z;
    const long m0 = (long)blockIdx.x * 128;
    const long n0 = (long)blockIdx.y * 128;

    const half_t* Ab = A  + (long)z * a_bs;
    const half_t* Bb = Bw + (long)z * b_bs;

    f32x4 acc[4][4];
#pragma unroll
    for (int i = 0; i < 4; i++)
#pragma unroll
        for (int j = 0; j < 4; j++)
            acc[i][j] = f32x4{0.f, 0.f, 0.f, 0.f};

    const int c0 = t, c1 = t + 256;
    const int r0 = c0 >> 2, kc0 = c0 & 3;
    const int r1 = c1 >> 2, kc1 = c1 & 3;

    const half_t* gA0 = Ab + (m0 + r0) * lda + kc0 * 8;
    const half_t* gA1 = Ab + (m0 + r1) * lda + kc1 * 8;
    const half_t* gB0 = Bb + (n0 + r0) * ldb + kc0 * 8;
    const half_t* gB1 = Bb + (n0 + r1) * ldb + kc1 * 8;
    half_t* lA0 = &As[c0 * 8];
    half_t* lA1 = &As[c1 * 8];
    half_t* lB0 = &Bs[c0 * 8];
    half_t* lB1 = &Bs[c1 * 8];

    int aoff[4], boff[4];
#pragma unroll
    for (int i = 0; i < 4; i++) aoff[i] = (wm * 64 + i * 16 + lanen) * 32 + quad * 8;
#pragma unroll
    for (int j = 0; j < 4; j++) boff[j] = (wn * 64 + j * 16 + lanen) * 32 + quad * 8;

    for (int k0 = 0; k0 < Kdim; k0 += 32) {
        __builtin_amdgcn_global_load_lds((gas_ptr)(gA0 + k0), (las_ptr)lA0, 16, 0, 0);
        __builtin_amdgcn_global_load_lds((gas_ptr)(gA1 + k0), (las_ptr)lA1, 16, 0, 0);
        __builtin_amdgcn_global_load_lds((gas_ptr)(gB0 + k0), (las_ptr)lB0, 16, 0, 0);
        __builtin_amdgcn_global_load_lds((gas_ptr)(gB1 + k0), (las_ptr)lB1, 16, 0, 0);
        __syncthreads();

        half8 af[4], bf[4];
#pragma unroll
        for (int i = 0; i < 4; i++) af[i] = *(const half8*)&As[aoff[i]];
#pragma unroll
        for (int j = 0; j < 4; j++) bf[j] = *(const half8*)&Bs[boff[j]];
#pragma unroll
        for (int i = 0; i < 4; i++)
#pragma unroll
            for (int j = 0; j < 4; j++)
                acc[i][j] = __builtin_amdgcn_mfma_f32_16x16x32_f16(af[i], bf[j], acc[i][j], 0, 0, 0);
        __syncthreads();
    }

    // C/D layout: col = lane&15, row = quad*4 + reg
#pragma unroll
    for (int i = 0; i < 4; i++) {
        long mrow = m0 + wm * 64 + i * 16 + quad * 4;
#pragma unroll
        for (int j = 0; j < 4; j++) {
            long gn = n0 + wn * 64 + j * 16 + lanen;
            f32x4 v = acc[i][j];
            if (MODE == 0) {
                float bb = bias[z * HID + gn];
                half_t h0 = (half_t)fmaxf(v[0] + bb, 0.f);
                half_t h1 = (half_t)fmaxf(v[1] + bb, 0.f);
                half_t h2 = (half_t)fmaxf(v[2] + bb, 0.f);
                half_t h3 = (half_t)fmaxf(v[3] + bb, 0.f);
                if (z == 0) {
                    long bidx = mrow >> 10;
                    long pos  = mrow & 1023;
                    half4v pk; pk[0] = h0; pk[1] = h1; pk[2] = h2; pk[3] = h3;
                    *(half4v*)(out2 + ((bidx * HID + gn) << 10) + pos) = pk;
                } else {
                    half_t* o = (half_t*)Out + (long)(z - 1) * o_bs;
                    o[(mrow + 0) * ldo + gn] = h0;
                    o[(mrow + 1) * ldo + gn] = h1;
                    o[(mrow + 2) * ldo + gn] = h2;
                    o[(mrow + 3) * ldo + gn] = h3;
                }
            } else {
                float* o = (float*)Out;
                float bb = bias[gn];
#pragma unroll
                for (int r = 0; r < 4; r++) o[(mrow + r) * ldo + gn] = fmaxf(v[r] + bb, 0.f);
            }
        }
    }
}

// ---------------- S = q k^T with fused exp, 128x256 tile ----------------
// Each wave-column (wn) spans exactly one 128-col stats block -> per-wave stats,
// no cross-wave reduction. Writes E = exp(s - m_loc) f16 + Mstat/Lstat per (row, kb).
__global__ __launch_bounds__(256, 2) void se_k(
    const half_t* __restrict__ Q, const half_t* __restrict__ K,
    half_t* __restrict__ E, float* __restrict__ Mstat, float* __restrict__ Lstat)
{
    __shared__ alignas(16) half_t As[128 * 32];
    __shared__ alignas(16) half_t Bs[256 * 32];

    const int t    = threadIdx.x;
    const int lane = t & 63;
    const int wave = t >> 6;
    const int wm   = wave >> 1;
    const int wn   = wave & 1;
    const int lanen = lane & 15;
    const int quad  = lane >> 4;
    const int z     = blockIdx.z;
    const long m0 = (long)blockIdx.x * 128;
    const long n0 = (long)blockIdx.y * 256;

    const half_t* Ab = Q + (long)z * SEQ * HID;
    const half_t* Bb = K + (long)z * SEQ * HID;

    f32x4 acc[4][8];
#pragma unroll
    for (int i = 0; i < 4; i++)
#pragma unroll
        for (int j = 0; j < 8; j++)
            acc[i][j] = f32x4{0.f, 0.f, 0.f, 0.f};

    // A: 512 chunks (2/thread), B: 1024 chunks (4/thread); chunk c -> row c>>2, kchunk c&3
    const half_t* gA[2]; half_t* lA[2];
    const half_t* gB[4]; half_t* lB[4];
#pragma unroll
    for (int s = 0; s < 2; s++) {
        int c = t + 256 * s;
        gA[s] = Ab + (m0 + (c >> 2)) * HID + (c & 3) * 8;
        lA[s] = &As[c * 8];
    }
#pragma unroll
    for (int s = 0; s < 4; s++) {
        int c = t + 256 * s;
        gB[s] = Bb + (n0 + (c >> 2)) * HID + (c & 3) * 8;
        lB[s] = &Bs[c * 8];
    }

    int aoff[4], boff[8];
#pragma unroll
    for (int i = 0; i < 4; i++) aoff[i] = (wm * 64 + i * 16 + lanen) * 32 + quad * 8;
#pragma unroll
    for (int j = 0; j < 8; j++) boff[j] = (wn * 128 + j * 16 + lanen) * 32 + quad * 8;

    for (int k0 = 0; k0 < HID; k0 += 32) {
#pragma unroll
        for (int s = 0; s < 2; s++)
            __builtin_amdgcn_global_load_lds((gas_ptr)(gA[s] + k0), (las_ptr)lA[s], 16, 0, 0);
#pragma unroll
        for (int s = 0; s < 4; s++)
            __builtin_amdgcn_global_load_lds((gas_ptr)(gB[s] + k0), (las_ptr)lB[s], 16, 0, 0);
        __syncthreads();

        half8 af[4], bf[8];
#pragma unroll
        for (int i = 0; i < 4; i++) af[i] = *(const half8*)&As[aoff[i]];
#pragma unroll
        for (int j = 0; j < 8; j++) bf[j] = *(const half8*)&Bs[boff[j]];
#pragma unroll
        for (int i = 0; i < 4; i++)
#pragma unroll
            for (int j = 0; j < 8; j++)
                acc[i][j] = __builtin_amdgcn_mfma_f32_16x16x32_f16(af[i], bf[j], acc[i][j], 0, 0, 0);
        __syncthreads();
    }

    // ---- epilogue: per-wave row max over this wave's 128 cols ----
    float mf[4][4];
#pragma unroll
    for (int i = 0; i < 4; i++)
#pragma unroll
        for (int r = 0; r < 4; r++) {
            float v = acc[i][0][r];
#pragma unroll
            for (int j = 1; j < 8; j++) v = fmaxf(v, acc[i][j][r]);
#pragma unroll
            for (int off = 8; off > 0; off >>= 1)
                v = fmaxf(v, __shfl_xor(v, off, 64));
            mf[i][r] = v;
        }

    // ---- exp + row partial sums + E store ----
    half_t* Eb = E + (long)z * SEQ * SEQ;
    float rs[4][4];
#pragma unroll
    for (int i = 0; i < 4; i++)
#pragma unroll
        for (int r = 0; r < 4; r++) rs[i][r] = 0.f;
#pragma unroll
    for (int i = 0; i < 4; i++) {
        long mrow = m0 + wm * 64 + i * 16 + quad * 4;
#pragma unroll
        for (int j = 0; j < 8; j++) {
            long gn = n0 + wn * 128 + j * 16 + lanen;
#pragma unroll
            for (int r = 0; r < 4; r++) {
                float e = __expf(acc[i][j][r] - mf[i][r]);
                rs[i][r] += e;
                Eb[(mrow + r) * SEQ + gn] = (half_t)e;
            }
        }
    }
#pragma unroll
    for (int i = 0; i < 4; i++)
#pragma unroll
        for (int r = 0; r < 4; r++) {
            float v = rs[i][r];
#pragma unroll
            for (int off = 8; off > 0; off >>= 1)
                v += __shfl_xor(v, off, 64);
            rs[i][r] = v;
        }

    // stats: kb = blockIdx.y*2 + wn; rows are wave-private -> no conflicts
    if (lanen == 0) {
        long base = ((long)z * 8 + blockIdx.y * 2 + wn) * SEQ + m0 + wm * 64;
#pragma unroll
        for (int i = 0; i < 4; i++)
#pragma unroll
            for (int r = 0; r < 4; r++) {
                Mstat[base + i * 16 + quad * 4 + r] = mf[i][r];
                Lstat[base + i * 16 + quad * 4 + r] = rs[i][r];
            }
    }
}

// ---------------- O = P vT with stat-merge rescale + normalize, 128x256 tile ----------------
__global__ __launch_bounds__(256, 2) void pv_k(
    const half_t* __restrict__ E, const half_t* __restrict__ vT,
    const float* __restrict__ Mstat, const float* __restrict__ Lstat,
    half_t* __restrict__ O16)
{
    __shared__ alignas(16) half_t As[128 * 32];
    __shared__ alignas(16) half_t Bs[256 * 32];
    __shared__ float scaleS[8][128];
    __shared__ float invS[128];

    const int t    = threadIdx.x;
    const int lane = t & 63;
    const int wave = t >> 6;
    const int wm   = wave >> 1;
    const int wn   = wave & 1;
    const int lanen = lane & 15;
    const int quad  = lane >> 4;
    const int z     = blockIdx.z;
    const long m0 = (long)blockIdx.x * 128;
    const long h0 = (long)blockIdx.y * 256;

    // prologue: merge per-col-block stats for this block's 128 rows
    if (t < 128) {
        float mv[8];
        float M = -1e30f;
#pragma unroll
        for (int kb = 0; kb < 8; kb++) {
            mv[kb] = Mstat[((long)z * 8 + kb) * SEQ + m0 + t];
            M = fmaxf(M, mv[kb]);
        }
        float ls = 0.f;
#pragma unroll
        for (int kb = 0; kb < 8; kb++) {
            float sc = __expf(mv[kb] - M);
            scaleS[kb][t] = sc;
            ls += Lstat[((long)z * 8 + kb) * SEQ + m0 + t] * sc;
        }
        invS[t] = 1.f / ls;
    }
    __syncthreads();

    const half_t* Ab = E  + (long)z * SEQ * SEQ;
    const half_t* Bb = vT + (long)z * HID * SEQ;

    f32x4 acc[4][8];
#pragma unroll
    for (int i = 0; i < 4; i++)
#pragma unroll
        for (int j = 0; j < 8; j++)
            acc[i][j] = f32x4{0.f, 0.f, 0.f, 0.f};

    const half_t* gA[2]; half_t* lA[2];
    const half_t* gB[4]; half_t* lB[4];
#pragma unroll
    for (int s = 0; s < 2; s++) {
        int c = t + 256 * s;
        gA[s] = Ab + (m0 + (c >> 2)) * SEQ + (c & 3) * 8;
        lA[s] = &As[c * 8];
    }
#pragma unroll
    for (int s = 0; s < 4; s++) {
        int c = t + 256 * s;
        gB[s] = Bb + (h0 + (c >> 2)) * SEQ + (c & 3) * 8;
        lB[s] = &Bs[c * 8];
    }

    int aoff[4], boff[8];
#pragma unroll
    for (int i = 0; i < 4; i++) aoff[i] = (wm * 64 + i * 16 + lanen) * 32 + quad * 8;
#pragma unroll
    for (int j = 0; j < 8; j++) boff[j] = (wn * 128 + j * 16 + lanen) * 32 + quad * 8;

    for (int k0 = 0; k0 < SEQ; k0 += 32) {
#pragma unroll
        for (int s = 0; s < 2; s++)
            __builtin_amdgcn_global_load_lds((gas_ptr)(gA[s] + k0), (las_ptr)lA[s], 16, 0, 0);
#pragma unroll
        for (int s = 0; s < 4; s++)
            __builtin_amdgcn_global_load_lds((gas_ptr)(gB[s] + k0), (las_ptr)lB[s], 16, 0, 0);
        __syncthreads();

        const int kb = k0 >> 7;
        half8 af[4], bf[8];
#pragma unroll
        for (int i = 0; i < 4; i++) {
            af[i] = *(const half8*)&As[aoff[i]];
            half_t sh = (half_t)scaleS[kb][wm * 64 + i * 16 + lanen];
            af[i] *= sh;   // per-row rescale exp(m_kb - M); A-operand row = lane&15
        }
#pragma unroll
        for (int j = 0; j < 8; j++) bf[j] = *(const half8*)&Bs[boff[j]];
#pragma unroll
        for (int i = 0; i < 4; i++)
#pragma unroll
            for (int j = 0; j < 8; j++)
                acc[i][j] = __builtin_amdgcn_mfma_f32_16x16x32_f16(af[i], bf[j], acc[i][j], 0, 0, 0);
        __syncthreads();
    }

    half_t* o = O16 + (long)z * SEQ * HID;
#pragma unroll
    for (int i = 0; i < 4; i++) {
        long mrow = m0 + wm * 64 + i * 16 + quad * 4;
        int rl = wm * 64 + i * 16 + quad * 4;
#pragma unroll
        for (int j = 0; j < 8; j++) {
            long gn = h0 + wn * 128 + j * 16 + lanen;
#pragma unroll
            for (int r = 0; r < 4; r++)
                o[(mrow + r) * HID + gn] = (half_t)(acc[i][j][r] * invS[rl + r]);
        }
    }
}

// ---------------- host ----------------
extern "C" void kernel_launch(void* const* d_in, const int* in_sizes, int n_in,
                              void* d_out, int out_size, void* d_ws, size_t ws_size,
                              hipStream_t stream) {
    const float* h  = (const float*)d_in[0];
    const float* Wv = (const float*)d_in[1];
    const float* bv = (const float*)d_in[2];
    const float* Wk = (const float*)d_in[3];
    const float* bk = (const float*)d_in[4];
    const float* Wq = (const float*)d_in[5];
    const float* bq = (const float*)d_in[6];
    const float* Wo = (const float*)d_in[7];
    const float* bo = (const float*)d_in[8];

    uint8_t* ws = (uint8_t*)d_ws;
    size_t off = 0;
    auto alloc = [&](size_t bytes) { size_t o = off; off += (bytes + 255) & ~(size_t)255; return o; };

    half_t* W16   = (half_t*)(ws + alloc((size_t)3 * HID * DIN * 2)); // [Wv][Wk][Wq]
    half_t* Wo16  = (half_t*)(ws + alloc((size_t)DIN * HID * 2));
    float*  biasq = (float*)(ws + alloc((size_t)3 * HID * 4));        // [bv][bk][bq]
    half_t* k16   = (half_t*)(ws + alloc((size_t)MTOT * HID * 2));
    half_t* q16   = (half_t*)(ws + alloc((size_t)MTOT * HID * 2));    // reused as O16 per group
    half_t* vT    = (half_t*)(ws + alloc((size_t)MTOT * HID * 2));    // [b][h][m]
    size_t h16_off = alloc((size_t)MTOT * DIN * 2);
    half_t* h16   = (half_t*)(ws + h16_off);
    half_t* O16 = q16;  // q dead after its group's se_k; O written strictly after

    // E + stats overlap the (dead-after-K1) h16 region onward
    size_t s_avail = ws_size > h16_off ? ws_size - h16_off : 0;
    size_t per_batch = (size_t)SEQ * SEQ * 2 + 2 * 8 * SEQ * 4;
    int GB = (int)(s_avail / per_batch);
    if (GB < 1)  GB = 1;
    if (GB > NB) GB = NB;
    half_t* Ebuf  = (half_t*)(ws + h16_off);
    float*  Mstat = (float*)(ws + h16_off + (size_t)GB * SEQ * SEQ * 2);
    float*  Lstat = Mstat + (size_t)GB * 8 * SEQ;

    // K0: conversions
    cvt_kernel<<<dim3((MTOT * DIN / 4 + 255) / 256), 256, 0, stream>>>(h, h16, MTOT * DIN / 4);
    cvt4_kernel<<<dim3((HID * DIN / 4 + 255) / 256, 4), 256, 0, stream>>>(
        Wv, Wk, Wq, Wo, W16, W16 + HID * DIN, W16 + 2 * HID * DIN, Wo16, HID * DIN / 4);
    pack_bias<<<dim3(1), 512, 0, stream>>>(bv, bk, bq, biasq);

    // K1: QKV projections (z: 0=V->vT, 1=K, 2=Q)
    gemm_k<0><<<dim3(MTOT / 128, HID / 128, 3), 256, 0, stream>>>(
        h16, DIN, 0,
        W16, DIN, (long)HID * DIN,
        (void*)k16, HID, (long)MTOT * HID,
        biasq, DIN, vT);

    for (int g0 = 0; g0 < NB; g0 += GB) {
        int gb = NB - g0 < GB ? NB - g0 : GB;
        // K2: E = exp(q k^T - m_loc) + stats  (128x256 tiles)
        se_k<<<dim3(SEQ / 128, SEQ / 256, gb), 256, 0, stream>>>(
            q16 + (size_t)g0 * SEQ * HID,
            k16 + (size_t)g0 * SEQ * HID,
            Ebuf, Mstat, Lstat);
        // K4: O = (scaled E) vT / lsum  (128x256 tiles)
        pv_k<<<dim3(SEQ / 128, HID / 256, gb), 256, 0, stream>>>(
            Ebuf, vT + (size_t)g0 * HID * SEQ,
            Mstat, Lstat,
            O16 + (size_t)g0 * SEQ * HID);
    }

    // K5: out = relu(O Wo^T + bo)  (f32 out)
    gemm_k<3><<<dim3(MTOT / 128, DIN / 128, 1), 256, 0, stream>>>(
        O16, HID, 0,
        Wo16, HID, 0,
        d_out, DIN, 0,
        bo, HID, nullptr);

    (void)in_sizes; (void)n_in; (void)out_size;
}